// Round 1
// baseline (12030.242 us; speedup 1.0000x reference)
//
#include <hip/hip_runtime.h>
#include <hip/hip_bf16.h>

namespace {
constexpr int kB   = 16384;
constexpr int kL   = 20;
constexpr int kS   = 64;
constexpr int kMsg = 64;
constexpr int kHid = 256;
constexpr int RPB  = 8;    // rows per block
constexpr int NTHR = 256;

__device__ __forceinline__ float wsum64(float v) {
  #pragma unroll
  for (int off = 32; off > 0; off >>= 1) v += __shfl_xor(v, off, 64);
  return v;
}

// out[r][tid] = relu(bias[tid] + sum_k in[r][k] * W[k*256 + tid]) for all RPB rows.
// Thread owns one output neuron across all rows -> each weight load feeds 8 FMAs.
template <int K>
__device__ __forceinline__ void dense_hid_relu(
    const float* __restrict__ W, const float* __restrict__ bv,
    const float (&in)[RPB][K], float (&outb)[RPB][kHid], int tid) {
  float acc[RPB];
  const float bias = bv[tid];
  #pragma unroll
  for (int r = 0; r < RPB; ++r) acc[r] = bias;
  const float* __restrict__ Wc = W + tid;
  for (int k4 = 0; k4 < K / 4; ++k4) {
    float4 xv[RPB];
    #pragma unroll
    for (int r = 0; r < RPB; ++r)
      xv[r] = *reinterpret_cast<const float4*>(&in[r][4 * k4]);
    #pragma unroll
    for (int j = 0; j < 4; ++j) {
      const float w = Wc[(size_t)(4 * k4 + j) * kHid];
      #pragma unroll
      for (int r = 0; r < RPB; ++r) {
        const float xx = (j == 0) ? xv[r].x : (j == 1) ? xv[r].y
                       : (j == 2) ? xv[r].z : xv[r].w;
        acc[r] = fmaf(xx, w, acc[r]);
      }
    }
  }
  #pragma unroll
  for (int r = 0; r < RPB; ++r) outb[r][tid] = fmaxf(acc[r], 0.0f);
}
}  // namespace

__global__ __launch_bounds__(NTHR) void actor_policy_kernel(
    const float* __restrict__ state,
    const float* __restrict__ uW1, const float* __restrict__ ub1,
    const float* __restrict__ uW2, const float* __restrict__ ub2,
    const float* __restrict__ uW3, const float* __restrict__ ub3,
    const float* __restrict__ aW1, const float* __restrict__ ab1,
    const float* __restrict__ aW2, const float* __restrict__ ab2,
    const float* __restrict__ aW3, const float* __restrict__ ab3,
    const float* __restrict__ mW1, const float* __restrict__ mb1,
    const float* __restrict__ mW2, const float* __restrict__ mb2,
    const float* __restrict__ mW3, const float* __restrict__ mb3,
    float* __restrict__ out) {
  __shared__ __align__(16) float msgs[RPB][kL][kMsg];  // 40 KB
  __shared__ __align__(16) float xm[RPB][2 * kMsg];    // 4 KB
  __shared__ __align__(16) float bufA[RPB][kHid];      // 8 KB
  __shared__ __align__(16) float bufB[RPB][kHid];      // 8 KB
  __shared__ __align__(16) float mcur[RPB][kMsg];      // 2 KB

  const int tid = threadIdx.x;
  const int wv  = tid >> 6;   // wave handles rows wv and wv+4
  const int ln  = tid & 63;
  const int r0 = wv, r1 = wv + 4;
  const int rowBase = blockIdx.x * RPB;

  for (int i = tid; i < RPB * kMsg; i += NTHR) (&mcur[0][0])[i] = 0.0f;
  __syncthreads();

  // ---------------- bottom-up pass: t = L-1 .. 0 ----------------
  for (int t = kL - 1; t >= 0; --t) {
    for (int i = tid; i < RPB * kS; i += NTHR) {
      const int r = i >> 6, s = i & 63;
      bufA[r][s] = state[((size_t)(rowBase + r) * kL + t) * kS + s];
    }
    __syncthreads();
    {  // h = normalize(x @ uW1 + ub1); xm = tanh([h, m])
      float a0 = ub1[ln], a1 = a0;
      #pragma unroll 4
      for (int k = 0; k < kS; ++k) {
        const float w = uW1[k * kMsg + ln];
        a0 = fmaf(bufA[r0][k], w, a0);
        a1 = fmaf(bufA[r1][k], w, a1);
      }
      const float i0 = 1.0f / fmaxf(sqrtf(wsum64(a0 * a0)), 1e-12f);
      const float i1 = 1.0f / fmaxf(sqrtf(wsum64(a1 * a1)), 1e-12f);
      xm[r0][ln] = tanhf(a0 * i0);
      xm[r1][ln] = tanhf(a1 * i1);
      xm[r0][kMsg + ln] = tanhf(mcur[r0][ln]);
      xm[r1][kMsg + ln] = tanhf(mcur[r1][ln]);
    }
    __syncthreads();
    {  // h2 = tanh(xm @ uW2 + ub2)
      float a0 = ub2[ln], a1 = a0;
      #pragma unroll 4
      for (int k = 0; k < 2 * kMsg; ++k) {
        const float w = uW2[k * kMsg + ln];
        a0 = fmaf(xm[r0][k], w, a0);
        a1 = fmaf(xm[r1][k], w, a1);
      }
      bufB[r0][ln] = tanhf(a0);
      bufB[r1][ln] = tanhf(a1);
    }
    __syncthreads();
    {  // msg = normalize(h2 @ uW3 + ub3); store msgs[t], carry
      float a0 = ub3[ln], a1 = a0;
      #pragma unroll 4
      for (int k = 0; k < kMsg; ++k) {
        const float w = uW3[k * kMsg + ln];
        a0 = fmaf(bufB[r0][k], w, a0);
        a1 = fmaf(bufB[r1][k], w, a1);
      }
      const float i0 = 1.0f / fmaxf(sqrtf(wsum64(a0 * a0)), 1e-12f);
      const float i1 = 1.0f / fmaxf(sqrtf(wsum64(a1 * a1)), 1e-12f);
      const float m0 = a0 * i0, m1 = a1 * i1;
      msgs[r0][t][ln] = m0;  msgs[r1][t][ln] = m1;
      mcur[r0][ln] = m0;     mcur[r1][ln] = m1;
    }
    __syncthreads();
  }

  for (int i = tid; i < RPB * kMsg; i += NTHR) (&mcur[0][0])[i] = 0.0f;
  __syncthreads();

  // ---------------- top-down pass: t = 0 .. L-1 ----------------
  for (int t = 0; t < kL; ++t) {
    xm[r0][ln] = tanhf(msgs[r0][t][ln]);
    xm[r1][ln] = tanhf(msgs[r1][t][ln]);
    xm[r0][kMsg + ln] = tanhf(mcur[r0][ln]);
    xm[r1][kMsg + ln] = tanhf(mcur[r1][ln]);
    __syncthreads();

    dense_hid_relu<2 * kMsg>(aW1, ab1, xm, bufA, tid);   // h1a
    __syncthreads();
    dense_hid_relu<kHid>(aW2, ab2, bufA, bufB, tid);     // h2a
    __syncthreads();

    {  // a = tanh(h2a @ aW3 + ab3)  (wave-per-row reduction)
      float p0 = 0.0f, p1 = 0.0f;
      #pragma unroll
      for (int j = 0; j < 4; ++j) {
        const float w3 = aW3[j * 64 + ln];
        p0 = fmaf(bufB[r0][j * 64 + ln], w3, p0);
        p1 = fmaf(bufB[r1][j * 64 + ln], w3, p1);
      }
      p0 = wsum64(p0);
      p1 = wsum64(p1);
      if (ln == 0) {
        const float b3 = ab3[0];
        out[(size_t)(rowBase + r0) * kL + t] = tanhf(p0 + b3);
        out[(size_t)(rowBase + r1) * kL + t] = tanhf(p1 + b3);
      }
    }

    dense_hid_relu<2 * kMsg>(mW1, mb1, xm, bufA, tid);   // h1m (bufA free: h2a done)
    __syncthreads();
    dense_hid_relu<kHid>(mW2, mb2, bufA, bufB, tid);     // h2m (bufB free: action done)
    __syncthreads();

    {  // md = normalize(h2m @ mW3 + mb3) -> carry
      float a0 = mb3[ln], a1 = a0;
      #pragma unroll 4
      for (int k = 0; k < kHid; ++k) {
        const float w = mW3[k * kMsg + ln];
        a0 = fmaf(bufB[r0][k], w, a0);
        a1 = fmaf(bufB[r1][k], w, a1);
      }
      const float i0 = 1.0f / fmaxf(sqrtf(wsum64(a0 * a0)), 1e-12f);
      const float i1 = 1.0f / fmaxf(sqrtf(wsum64(a1 * a1)), 1e-12f);
      mcur[r0][ln] = a0 * i0;
      mcur[r1][ln] = a1 * i1;
    }
    __syncthreads();
  }
}

extern "C" void kernel_launch(void* const* d_in, const int* in_sizes, int n_in,
                              void* d_out, int out_size, void* d_ws, size_t ws_size,
                              hipStream_t stream) {
  (void)in_sizes; (void)n_in; (void)d_ws; (void)ws_size; (void)out_size;
  const float* state = (const float*)d_in[0];
  const float* uW1 = (const float*)d_in[1];
  const float* ub1 = (const float*)d_in[2];
  const float* uW2 = (const float*)d_in[3];
  const float* ub2 = (const float*)d_in[4];
  const float* uW3 = (const float*)d_in[5];
  const float* ub3 = (const float*)d_in[6];
  const float* aW1 = (const float*)d_in[7];
  const float* ab1 = (const float*)d_in[8];
  const float* aW2 = (const float*)d_in[9];
  const float* ab2 = (const float*)d_in[10];
  const float* aW3 = (const float*)d_in[11];
  const float* ab3 = (const float*)d_in[12];
  const float* mW1 = (const float*)d_in[13];
  const float* mb1 = (const float*)d_in[14];
  const float* mW2 = (const float*)d_in[15];
  const float* mb2 = (const float*)d_in[16];
  const float* mW3 = (const float*)d_in[17];
  const float* mb3 = (const float*)d_in[18];
  float* out = (float*)d_out;

  dim3 grid(kB / RPB);   // 2048 blocks
  dim3 block(NTHR);
  hipLaunchKernelGGL(actor_policy_kernel, grid, block, 0, stream,
                     state, uW1, ub1, uW2, ub2, uW3, ub3,
                     aW1, ab1, aW2, ab2, aW3, ab3,
                     mW1, mb1, mW2, mb2, mW3, mb3, out);
}

// Round 2
// 2625.407 us; speedup vs baseline: 4.5822x; 4.5822x over previous
//
#include <hip/hip_runtime.h>

typedef unsigned int u32;
typedef unsigned short u16;
typedef short s16x8 __attribute__((ext_vector_type(8)));
typedef float f32x4 __attribute__((ext_vector_type(4)));

namespace {
constexpr int kB   = 16384;
constexpr int kL   = 20;
constexpr int RPB  = 16;    // rows per block (one M-tile)
constexpr int NTHR = 512;   // 8 waves

// packed-weight offsets in d_ws (bf16 elements). layout per (kt, n):
// [((kt*N + n)*2 + plane)*32 + kin], kin = k&31, plane 0=hi 1=lo
constexpr int OFF_A1 = 0;                    // 128x256
constexpr int OFF_A2 = OFF_A1 + 128*256*2;   // 256x256
constexpr int OFF_M1 = OFF_A2 + 256*256*2;   // 128x256
constexpr int OFF_M2 = OFF_M1 + 128*256*2;   // 256x256
constexpr int OFF_M3 = OFF_M2 + 256*256*2;   // 256x64
constexpr int PACK_ELEMS = OFF_M3 + 256*64*2; // 425984

__device__ __forceinline__ u16 f2bf(float x) {
  u32 b = __builtin_bit_cast(u32, x);
  b += 0x7FFFu + ((b >> 16) & 1u);   // RTN-even
  return (u16)(b >> 16);
}
__device__ __forceinline__ float bf2f(u16 h) {
  return __builtin_bit_cast(float, (u32)h << 16);
}
__device__ __forceinline__ void split2(float x, u16& hi, u16& lo) {
  hi = f2bf(x);
  lo = f2bf(x - bf2f(hi));
}
__device__ __forceinline__ float wsum64(float v) {
  #pragma unroll
  for (int off = 32; off > 0; off >>= 1) v += __shfl_xor(v, off, 64);
  return v;
}
__device__ __forceinline__ s16x8 ld_frag(const u16* p) {
  return *reinterpret_cast<const s16x8*>(__builtin_assume_aligned(p, 16));
}
__device__ __forceinline__ f32x4 mfma16(s16x8 a, s16x8 b, f32x4 c) {
  return __builtin_amdgcn_mfma_f32_16x16x32_bf16(a, b, c, 0, 0, 0);
}

// C[m][n] = act(sum_k A[m][k]*B[k][n] + bias[n]) via split-bf16 (3 mfma/tile).
// Wave wv owns ntiles {2wv, 2wv+1}. A planes in LDS (hi/lo), B packed in ws.
template <int K, int N, bool RELU>
__device__ __forceinline__ void mfma_layer(
    const u16* __restrict__ Ah, const u16* __restrict__ Al, const int lda,
    const u16* __restrict__ Bp, const float* __restrict__ bias,
    u16* __restrict__ Oh, u16* __restrict__ Ol, const int ldo,
    const int wv, const int r15, const int g) {
  constexpr int KT = K / 32;
  constexpr int NT = N / 16;
  const int nt0 = wv * 2;
  if (nt0 >= NT) return;
  const int c0 = nt0 * 16 + r15;
  f32x4 acc0 = {0.f, 0.f, 0.f, 0.f}, acc1 = acc0;
  #pragma unroll
  for (int kt = 0; kt < KT; ++kt) {
    const int abase = r15 * lda + kt * 32 + g * 8;
    s16x8 ah = ld_frag(Ah + abase);
    s16x8 al = ld_frag(Al + abase);
    const u16* b0 = Bp + (size_t)((kt * N + c0) * 2) * 32 + g * 8;
    const u16* b1 = Bp + (size_t)((kt * N + c0 + 16) * 2) * 32 + g * 8;
    s16x8 b0h = ld_frag(b0), b0l = ld_frag(b0 + 32);
    s16x8 b1h = ld_frag(b1), b1l = ld_frag(b1 + 32);
    acc0 = mfma16(ah, b0h, acc0);
    acc0 = mfma16(al, b0h, acc0);
    acc0 = mfma16(ah, b0l, acc0);
    acc1 = mfma16(ah, b1h, acc1);
    acc1 = mfma16(al, b1h, acc1);
    acc1 = mfma16(ah, b1l, acc1);
  }
  #pragma unroll
  for (int nt = 0; nt < 2; ++nt) {
    const int col = c0 + nt * 16;
    const float bb = bias[col];
    const f32x4 a = nt ? acc1 : acc0;
    #pragma unroll
    for (int i = 0; i < 4; ++i) {
      const int row = g * 4 + i;
      float v = a[i] + bb;
      if (RELU) v = fmaxf(v, 0.f);
      u16 h, l;
      split2(v, h, l);
      Oh[row * ldo + col] = h;
      Ol[row * ldo + col] = l;
    }
  }
}

// m3: 256 -> 64, no relu, f32 output (pre-normalize)
__device__ __forceinline__ void mfma_m3(
    const u16* __restrict__ Ah, const u16* __restrict__ Al, const int lda,
    const u16* __restrict__ Bp, const float* __restrict__ bias,
    float* __restrict__ Om, const int ldo,
    const int wv, const int r15, const int g) {
  constexpr int K = 256, N = 64, KT = K / 32;
  const int nt0 = wv * 2;
  if (nt0 >= N / 16) return;
  const int c0 = nt0 * 16 + r15;
  f32x4 acc0 = {0.f, 0.f, 0.f, 0.f}, acc1 = acc0;
  #pragma unroll
  for (int kt = 0; kt < KT; ++kt) {
    const int abase = r15 * lda + kt * 32 + g * 8;
    s16x8 ah = ld_frag(Ah + abase);
    s16x8 al = ld_frag(Al + abase);
    const u16* b0 = Bp + (size_t)((kt * N + c0) * 2) * 32 + g * 8;
    const u16* b1 = Bp + (size_t)((kt * N + c0 + 16) * 2) * 32 + g * 8;
    s16x8 b0h = ld_frag(b0), b0l = ld_frag(b0 + 32);
    s16x8 b1h = ld_frag(b1), b1l = ld_frag(b1 + 32);
    acc0 = mfma16(ah, b0h, acc0);
    acc0 = mfma16(al, b0h, acc0);
    acc0 = mfma16(ah, b0l, acc0);
    acc1 = mfma16(ah, b1h, acc1);
    acc1 = mfma16(al, b1h, acc1);
    acc1 = mfma16(ah, b1l, acc1);
  }
  #pragma unroll
  for (int nt = 0; nt < 2; ++nt) {
    const int col = c0 + nt * 16;
    const float bb = bias[col];
    const f32x4 a = nt ? acc1 : acc0;
    #pragma unroll
    for (int i = 0; i < 4; ++i) Om[(g * 4 + i) * ldo + col] = a[i] + bb;
  }
}

struct BU {  // bottom-up phase locals
  float sW1[64][64];
  float sW2[128][64];
  float sW3[64][64];
  float bufX[RPB][132];  // xm_bu (128) + pad
  float bufS[RPB][68];   // x / h2 staging
};
struct TD {  // top-down phase locals
  u16 xmH[RPB][136], xmL[RPB][136];
  u16 bAH[RPB][264], bAL[RPB][264];
  u16 bBH[RPB][264], bBL[RPB][264];
  float md[RPB][68];
};
}  // namespace

__global__ __launch_bounds__(256) void prep_weights_kernel(
    const float* __restrict__ aW1, const float* __restrict__ aW2,
    const float* __restrict__ mW1, const float* __restrict__ mW2,
    const float* __restrict__ mW3, u16* __restrict__ ws) {
  const float* Ws[5] = {aW1, aW2, mW1, mW2, mW3};
  const int Ns[5] = {256, 256, 256, 256, 64};
  const int dst[5] = {OFF_A1, OFF_A2, OFF_M1, OFF_M2, OFF_M3};
  const int cnt[5] = {32768, 65536, 32768, 65536, 16384};
  const int total = 212992;
  for (int e = blockIdx.x * 256 + threadIdx.x; e < total;
       e += gridDim.x * 256) {
    int l = 0, base = 0;
    while (e - base >= cnt[l]) { base += cnt[l]; ++l; }
    const int s = e - base, N = Ns[l];
    const int k = s / N, n = s % N;
    const float w = Ws[l][s];
    u16 hi, lo;
    split2(w, hi, lo);
    const int kt = k >> 5, kin = k & 31;
    const int ob = dst[l] + ((kt * N + n) * 2) * 32 + kin;
    ws[ob] = hi;
    ws[ob + 32] = lo;
  }
}

__global__ __launch_bounds__(NTHR) void actor_mfma_kernel(
    const float* __restrict__ state,
    const float* __restrict__ uW1, const float* __restrict__ ub1,
    const float* __restrict__ uW2, const float* __restrict__ ub2,
    const float* __restrict__ uW3, const float* __restrict__ ub3,
    const float* __restrict__ ab1, const float* __restrict__ ab2,
    const float* __restrict__ aW3, const float* __restrict__ ab3,
    const float* __restrict__ mb1, const float* __restrict__ mb2,
    const float* __restrict__ mb3,
    const u16* __restrict__ wsp, float* __restrict__ out) {
  __shared__ __align__(16) union { BU bu; TD td; } S;
  __shared__ u16 msgs[RPB][kL][64];
  __shared__ float mcur[RPB][64];

  const int tid = threadIdx.x;
  const int wv = tid >> 6, lane = tid & 63;
  const int r15 = lane & 15, g = lane >> 4;
  const int rA = 2 * wv, rB = 2 * wv + 1;
  const int rowBase = blockIdx.x * RPB;

  // ---- stage u-weights once ----
  for (int i = tid; i < 64 * 64; i += NTHR) S.bu.sW1[i >> 6][i & 63] = uW1[i];
  for (int i = tid; i < 128 * 64; i += NTHR) S.bu.sW2[i >> 6][i & 63] = uW2[i];
  for (int i = tid; i < 64 * 64; i += NTHR) S.bu.sW3[i >> 6][i & 63] = uW3[i];
  for (int i = tid; i < RPB * 64; i += NTHR) (&mcur[0][0])[i] = 0.f;
  const float bu1 = ub1[lane], bu2 = ub2[lane], bu3 = ub3[lane];
  __syncthreads();

  // ---------------- bottom-up: t = L-1 .. 0 (f32 VALU) ----------------
  for (int t = kL - 1; t >= 0; --t) {
    for (int i = tid; i < RPB * 64; i += NTHR) {
      const int r = i >> 6, s = i & 63;
      S.bu.bufS[r][s] = state[((size_t)(rowBase + r) * kL + t) * 64 + s];
    }
    __syncthreads();
    {  // u1: h = normalize(x@uW1+b); bufX = tanh([h, m])
      float a0 = bu1, a1 = bu1;
      #pragma unroll 4
      for (int k = 0; k < 64; ++k) {
        const float w = S.bu.sW1[k][lane];
        a0 = fmaf(S.bu.bufS[rA][k], w, a0);
        a1 = fmaf(S.bu.bufS[rB][k], w, a1);
      }
      const float i0 = 1.f / fmaxf(sqrtf(wsum64(a0 * a0)), 1e-12f);
      const float i1 = 1.f / fmaxf(sqrtf(wsum64(a1 * a1)), 1e-12f);
      S.bu.bufX[rA][lane] = tanhf(a0 * i0);
      S.bu.bufX[rB][lane] = tanhf(a1 * i1);
      S.bu.bufX[rA][64 + lane] = tanhf(mcur[rA][lane]);
      S.bu.bufX[rB][64 + lane] = tanhf(mcur[rB][lane]);
    }
    {  // u2: h2 = tanh(xm@uW2+b)  (intra-wave deps only)
      float a0 = bu2, a1 = bu2;
      #pragma unroll 4
      for (int k = 0; k < 128; ++k) {
        const float w = S.bu.sW2[k][lane];
        a0 = fmaf(S.bu.bufX[rA][k], w, a0);
        a1 = fmaf(S.bu.bufX[rB][k], w, a1);
      }
      S.bu.bufS[rA][lane] = tanhf(a0);
      S.bu.bufS[rB][lane] = tanhf(a1);
    }
    {  // u3: msg = normalize(h2@uW3+b)
      float a0 = bu3, a1 = bu3;
      #pragma unroll 4
      for (int k = 0; k < 64; ++k) {
        const float w = S.bu.sW3[k][lane];
        a0 = fmaf(S.bu.bufS[rA][k], w, a0);
        a1 = fmaf(S.bu.bufS[rB][k], w, a1);
      }
      const float i0 = 1.f / fmaxf(sqrtf(wsum64(a0 * a0)), 1e-12f);
      const float i1 = 1.f / fmaxf(sqrtf(wsum64(a1 * a1)), 1e-12f);
      const float m0 = a0 * i0, m1 = a1 * i1;
      msgs[rA][t][lane] = f2bf(m0);
      msgs[rB][t][lane] = f2bf(m1);
      mcur[rA][lane] = m0;
      mcur[rB][lane] = m1;
    }
    __syncthreads();
  }

  for (int i = tid; i < RPB * 64; i += NTHR) (&mcur[0][0])[i] = 0.f;
  __syncthreads();

  // ---------------- top-down: t = 0 .. L-1 (MFMA) ----------------
  const float ab3v = ab3[0];
  for (int t = 0; t < kL; ++t) {
    // xm = tanh([mu, m]) -> hi/lo planes
    for (int i = tid; i < RPB * 128; i += NTHR) {
      const int r = i >> 7, c = i & 127;
      const float v = (c < 64) ? bf2f(msgs[r][t][c]) : mcur[r][c - 64];
      u16 h, l;
      split2(tanhf(v), h, l);
      S.td.xmH[r][c] = h;
      S.td.xmL[r][c] = l;
    }
    __syncthreads();
    mfma_layer<128, 256, true>(&S.td.xmH[0][0], &S.td.xmL[0][0], 136,
                               wsp + OFF_A1, ab1,
                               &S.td.bAH[0][0], &S.td.bAL[0][0], 264,
                               wv, r15, g);
    __syncthreads();
    mfma_layer<256, 256, true>(&S.td.bAH[0][0], &S.td.bAL[0][0], 264,
                               wsp + OFF_A2, ab2,
                               &S.td.bBH[0][0], &S.td.bBL[0][0], 264,
                               wv, r15, g);
    __syncthreads();
    {  // a3: out = tanh(h2a @ aW3 + b)  (wave-per-2-rows VALU)
      float p0 = 0.f, p1 = 0.f;
      #pragma unroll
      for (int j = 0; j < 4; ++j) {
        const int c = j * 64 + lane;
        const float w = aW3[c];
        p0 = fmaf(bf2f(S.td.bBH[rA][c]) + bf2f(S.td.bBL[rA][c]), w, p0);
        p1 = fmaf(bf2f(S.td.bBH[rB][c]) + bf2f(S.td.bBL[rB][c]), w, p1);
      }
      p0 = wsum64(p0);
      p1 = wsum64(p1);
      if (lane == 0) {
        out[(size_t)(rowBase + rA) * kL + t] = tanhf(p0 + ab3v);
        out[(size_t)(rowBase + rB) * kL + t] = tanhf(p1 + ab3v);
      }
    }
    // L1m (writes bA; all bA readers finished at barrier after L2a)
    mfma_layer<128, 256, true>(&S.td.xmH[0][0], &S.td.xmL[0][0], 136,
                               wsp + OFF_M1, mb1,
                               &S.td.bAH[0][0], &S.td.bAL[0][0], 264,
                               wv, r15, g);
    __syncthreads();
    mfma_layer<256, 256, true>(&S.td.bAH[0][0], &S.td.bAL[0][0], 264,
                               wsp + OFF_M2, mb2,
                               &S.td.bBH[0][0], &S.td.bBL[0][0], 264,
                               wv, r15, g);
    __syncthreads();
    mfma_m3(&S.td.bBH[0][0], &S.td.bBL[0][0], 264, wsp + OFF_M3, mb3,
            &S.td.md[0][0], 68, wv, r15, g);
    __syncthreads();
    {  // md normalize -> mcur
      const float v0 = S.td.md[rA][lane], v1 = S.td.md[rB][lane];
      const float i0 = 1.f / fmaxf(sqrtf(wsum64(v0 * v0)), 1e-12f);
      const float i1 = 1.f / fmaxf(sqrtf(wsum64(v1 * v1)), 1e-12f);
      mcur[rA][lane] = v0 * i0;
      mcur[rB][lane] = v1 * i1;
    }
    __syncthreads();
  }
}

extern "C" void kernel_launch(void* const* d_in, const int* in_sizes, int n_in,
                              void* d_out, int out_size, void* d_ws, size_t ws_size,
                              hipStream_t stream) {
  (void)in_sizes; (void)n_in; (void)out_size; (void)ws_size;
  const float* state = (const float*)d_in[0];
  const float* uW1 = (const float*)d_in[1];
  const float* ub1 = (const float*)d_in[2];
  const float* uW2 = (const float*)d_in[3];
  const float* ub2 = (const float*)d_in[4];
  const float* uW3 = (const float*)d_in[5];
  const float* ub3 = (const float*)d_in[6];
  const float* aW1 = (const float*)d_in[7];
  const float* ab1 = (const float*)d_in[8];
  const float* aW2 = (const float*)d_in[9];
  const float* ab2 = (const float*)d_in[10];
  const float* aW3 = (const float*)d_in[11];
  const float* ab3 = (const float*)d_in[12];
  const float* mW1 = (const float*)d_in[13];
  const float* mb1 = (const float*)d_in[14];
  const float* mW2 = (const float*)d_in[15];
  const float* mb2 = (const float*)d_in[16];
  const float* mW3 = (const float*)d_in[17];
  const float* mb3 = (const float*)d_in[18];
  u16* wsp = (u16*)d_ws;
  float* out = (float*)d_out;

  hipLaunchKernelGGL(prep_weights_kernel, dim3(832), dim3(256), 0, stream,
                     aW1, aW2, mW1, mW2, mW3, wsp);
  hipLaunchKernelGGL(actor_mfma_kernel, dim3(kB / RPB), dim3(NTHR), 0, stream,
                     state, uW1, ub1, uW2, ub2, uW3, ub3,
                     ab1, ab2, aW3, ab3, mb1, mb2, mb3, wsp, out);
}